// Round 9
// baseline (779.014 us; speedup 1.0000x reference)
//
#include <hip/hip_runtime.h>
#include <hip/hip_bf16.h>

// MetaMultiParallelMLP on MFMA (gfx950): G=16, D=8, W=64, IN_CH=3, OUT_CH=4,
// skip-concat of x before layer 5. B=1, N=65536. fp32 in/out.
//
// Split-bf16 MFMA: v = vh + vl; W*H ~= Wh*Hh + Wh*Hl + Wl*Hh.
// Register-chained activations (sigma-permuted weight columns make layer k's
// C fragment == layer k+1's B fragment; no LDS, no barriers).
// Round 9: NT=2 (32 pts/wave, 3 waves/SIMD) + software-pipelined weight loads:
//   phase1: 16 hi-MFMAs  -> issue Al batch (latency covered by phase2)
//   phase2: 16 hi-MFMAs  -> Al ready
//   phase3: 16 lo-MFMAs  -> prefetch NEXT layer's Ah (covered by cvt_all VALU)
// s_setprio(1) around MFMA phases (independent waves -> attn-like case).

#define NG 16
#define NPTS 65536
#define NT 2                            // nt-tiles (16 points each) per wave

typedef __attribute__((ext_vector_type(8))) short bf16x8;
typedef __attribute__((ext_vector_type(4))) float f32x4;
typedef __attribute__((ext_vector_type(4))) int i32x4;

#define SLOT_ELEMS 4096                 // one [64][64] bf16 slot
#define GROUP_ELEMS (10 * SLOT_ELEMS)   // 0: L0 x-part, 1..7: dense (5=h-part), 8: L5 x-part, 9: w_out
#define WBUF_ELEMS (NG * GROUP_ELEMS)

#define MFMA16(a, b, c) __builtin_amdgcn_mfma_f32_16x16x32_bf16((a), (b), (c), 0, 0, 0)

// ---------- bf16 helpers ----------
__device__ __forceinline__ unsigned short f2bf(float f) {
  unsigned u = __builtin_bit_cast(unsigned, f);
  u += 0x7FFFu + ((u >> 16) & 1u);
  return (unsigned short)(u >> 16);
}
__device__ __forceinline__ float bf2f(unsigned short h) {
  return __builtin_bit_cast(float, ((unsigned)h) << 16);
}
__device__ __forceinline__ unsigned pkbf(float a, float b) {
  __hip_bfloat162 t = __float22bfloat162_rn(make_float2(a, b));  // a -> low 16, b -> high 16
  unsigned u;
  __builtin_memcpy(&u, &t, 4);
  return u;
}
__device__ __forceinline__ float lo2f(unsigned u) { return __builtin_bit_cast(float, u << 16); }
__device__ __forceinline__ float hi2f(unsigned u) { return __builtin_bit_cast(float, u & 0xFFFF0000u); }
__device__ __forceinline__ bf16x8 pack4(unsigned a, unsigned b, unsigned cc, unsigned d) {
  i32x4 t;
  t[0] = (int)a; t[1] = (int)b; t[2] = (int)cc; t[3] = (int)d;
  return __builtin_bit_cast(bf16x8, t);
}

// sigma: MFMA k-position -> weight source column
__device__ __forceinline__ int sig(int k) {
  int kt = k >> 5, qq = (k >> 3) & 3, j = k & 7;
  return (kt * 2 + (j >> 2)) * 16 + qq * 4 + (j & 3);
}

// ---------- prep: split fp32 weights into bf16 hi/lo, column-permuted ----------
__global__ __launch_bounds__(256) void prep_weights(
    const float* __restrict__ w0, const float* __restrict__ w1,
    const float* __restrict__ w2, const float* __restrict__ w3,
    const float* __restrict__ w4, const float* __restrict__ w5,
    const float* __restrict__ w6, const float* __restrict__ w7,
    const float* __restrict__ w_out,
    unsigned short* __restrict__ whi, unsigned short* __restrict__ wlo) {
  int idx = blockIdx.x * 256 + threadIdx.x;
  if (idx >= WBUF_ELEMS) return;
  int g = idx / GROUP_ELEMS;
  int rem = idx - g * GROUP_ELEMS;
  int slot = rem / SLOT_ELEMS;
  int rc = rem - slot * SLOT_ELEMS;
  int row = rc >> 6, col = rc & 63;
  int sc = sig(col);
  float v = 0.0f;
  switch (slot) {
    case 0: if (col < 3) v = w0[g * 192 + row * 3 + col]; break;          // x-part: no sigma
    case 1: v = w1[g * 4096 + row * 64 + sc]; break;
    case 2: v = w2[g * 4096 + row * 64 + sc]; break;
    case 3: v = w3[g * 4096 + row * 64 + sc]; break;
    case 4: v = w4[g * 4096 + row * 64 + sc]; break;
    case 5: v = w5[g * 4288 + row * 67 + 3 + sc]; break;                  // h-part cols
    case 6: v = w6[g * 4096 + row * 64 + sc]; break;
    case 7: v = w7[g * 4096 + row * 64 + sc]; break;
    case 8: if (col < 3) v = w5[g * 4288 + row * 67 + col]; break;        // x-part: no sigma
    case 9: if (row < 4) v = w_out[g * 256 + row * 64 + sc]; break;
  }
  unsigned short h = f2bf(v);
  whi[idx] = h;
  wlo[idx] = f2bf(v - bf2f(h));
}

// ---------- device pieces ----------
__device__ __forceinline__ void zeroC(f32x4 (&C)[4][NT]) {
#pragma unroll
  for (int mt = 0; mt < 4; ++mt)
#pragma unroll
    for (int nt = 0; nt < NT; ++nt) {
      f32x4 z = {0.f, 0.f, 0.f, 0.f};
      C[mt][nt] = z;
    }
}

// bias+relu for all nt, pack next-layer B frags; optionally write relu'd back
// to C (only needed after the last hidden layer, for hfinal).
template <bool KEEPC>
__device__ __forceinline__ void cvt_all(f32x4 (&C)[4][NT], const float4* __restrict__ bias4,
                                        int q, bf16x8 (&Bh)[NT][2], bf16x8 (&Bl)[NT][2]) {
  float4 bs[4];
#pragma unroll
  for (int mt = 0; mt < 4; ++mt) bs[mt] = bias4[mt * 4 + q];
#pragma unroll
  for (int nt = 0; nt < NT; ++nt) {
    float v[4][4];
#pragma unroll
    for (int mt = 0; mt < 4; ++mt) {
      f32x4 cc = C[mt][nt];
      float t0 = fmaxf(cc[0] + bs[mt].x, 0.f);
      float t1 = fmaxf(cc[1] + bs[mt].y, 0.f);
      float t2 = fmaxf(cc[2] + bs[mt].z, 0.f);
      float t3 = fmaxf(cc[3] + bs[mt].w, 0.f);
      v[mt][0] = t0; v[mt][1] = t1; v[mt][2] = t2; v[mt][3] = t3;
      if (KEEPC) {
        cc[0] = t0; cc[1] = t1; cc[2] = t2; cc[3] = t3;
        C[mt][nt] = cc;
      }
    }
#pragma unroll
    for (int kt = 0; kt < 2; ++kt) {
      const float* a = v[2 * kt];
      const float* b = v[2 * kt + 1];
      unsigned u0 = pkbf(a[0], a[1]), u1 = pkbf(a[2], a[3]);
      unsigned u2 = pkbf(b[0], b[1]), u3 = pkbf(b[2], b[3]);
      Bh[nt][kt] = pack4(u0, u1, u2, u3);
      unsigned l0 = pkbf(a[0] - lo2f(u0), a[1] - hi2f(u0));
      unsigned l1 = pkbf(a[2] - lo2f(u1), a[3] - hi2f(u1));
      unsigned l2 = pkbf(b[0] - lo2f(u2), b[1] - hi2f(u2));
      unsigned l3 = pkbf(b[2] - lo2f(u3), b[3] - hi2f(u3));
      Bl[nt][kt] = pack4(l0, l1, l2, l3);
    }
  }
}

// dense 64->64, software-pipelined. Ah holds THIS layer's hi frags on entry;
// on exit it holds wh_next's hi frags (in flight, consumed next layer).
__device__ __forceinline__ void dense_pipe(const unsigned short* __restrict__ wl,
                                           const unsigned short* __restrict__ wh_next,
                                           int q, int c,
                                           const bf16x8 (&Bh)[NT][2], const bf16x8 (&Bl)[NT][2],
                                           f32x4 (&C)[4][NT], bf16x8 (&Ah)[4][2]) {
  // phase 1: hi MFMAs, mt 0..1 (16)
  __builtin_amdgcn_s_setprio(1);
#pragma unroll
  for (int mt = 0; mt < 2; ++mt)
#pragma unroll
    for (int kt = 0; kt < 2; ++kt)
#pragma unroll
      for (int nt = 0; nt < NT; ++nt) {
        C[mt][nt] = MFMA16(Ah[mt][kt], Bh[nt][kt], C[mt][nt]);
        C[mt][nt] = MFMA16(Ah[mt][kt], Bl[nt][kt], C[mt][nt]);
      }
  __builtin_amdgcn_s_setprio(0);

  // issue Al batch (8 loads) -- latency covered by phase 2
  bf16x8 Al[4][2];
#pragma unroll
  for (int mt = 0; mt < 4; ++mt)
#pragma unroll
    for (int kt = 0; kt < 2; ++kt)
      Al[mt][kt] = *(const bf16x8*)(wl + (mt * 16 + c) * 64 + kt * 32 + q * 8);

  // phase 2: hi MFMAs, mt 2..3 (16)
  __builtin_amdgcn_s_setprio(1);
#pragma unroll
  for (int mt = 2; mt < 4; ++mt)
#pragma unroll
    for (int kt = 0; kt < 2; ++kt)
#pragma unroll
      for (int nt = 0; nt < NT; ++nt) {
        C[mt][nt] = MFMA16(Ah[mt][kt], Bh[nt][kt], C[mt][nt]);
        C[mt][nt] = MFMA16(Ah[mt][kt], Bl[nt][kt], C[mt][nt]);
      }

  // phase 3: lo MFMAs (16); Ah regs become dead here
#pragma unroll
  for (int mt = 0; mt < 4; ++mt)
#pragma unroll
    for (int kt = 0; kt < 2; ++kt)
#pragma unroll
      for (int nt = 0; nt < NT; ++nt)
        C[mt][nt] = MFMA16(Al[mt][kt], Bh[nt][kt], C[mt][nt]);
  __builtin_amdgcn_s_setprio(0);

  // prefetch next layer's Ah into the freed regs -- covered by cvt_all's VALU
#pragma unroll
  for (int mt = 0; mt < 4; ++mt)
#pragma unroll
    for (int kt = 0; kt < 2; ++kt)
      Ah[mt][kt] = *(const bf16x8*)(wh_next + (mt * 16 + c) * 64 + kt * 32 + q * 8);
}

// x contribution (k=0..2 live in kt=0, q'==0 lanes, j order = feature order)
__device__ __forceinline__ void xpart(const unsigned short* __restrict__ wh,
                                      const unsigned short* __restrict__ wl,
                                      int q, int c, const float (&xr)[NT][3], f32x4 (&C)[4][NT]) {
  bf16x8 Bxh[NT], Bxl[NT];
#pragma unroll
  for (int nt = 0; nt < NT; ++nt) {
    unsigned u0 = 0, u1 = 0, l0 = 0, l1 = 0;
    if (q == 0) {
      u0 = pkbf(xr[nt][0], xr[nt][1]);
      u1 = pkbf(xr[nt][2], 0.f);
      l0 = pkbf(xr[nt][0] - lo2f(u0), xr[nt][1] - hi2f(u0));
      l1 = pkbf(xr[nt][2] - lo2f(u1), 0.f);
    }
    Bxh[nt] = pack4(u0, u1, 0, 0);
    Bxl[nt] = pack4(l0, l1, 0, 0);
  }
#pragma unroll
  for (int mt = 0; mt < 4; ++mt) {
    bf16x8 Ah = *(const bf16x8*)(wh + (mt * 16 + c) * 64 + q * 8);  // kt=0 only
    bf16x8 Al = *(const bf16x8*)(wl + (mt * 16 + c) * 64 + q * 8);
#pragma unroll
    for (int nt = 0; nt < NT; ++nt) {
      C[mt][nt] = MFMA16(Ah, Bxh[nt], C[mt][nt]);
      C[mt][nt] = MFMA16(Ah, Bxl[nt], C[mt][nt]);
      C[mt][nt] = MFMA16(Al, Bxh[nt], C[mt][nt]);
    }
  }
}

__global__ __launch_bounds__(256, 3) void mlp_mfma_kernel(
    const float* __restrict__ x,
    const float* __restrict__ b0, const float* __restrict__ b1,
    const float* __restrict__ b2, const float* __restrict__ b3,
    const float* __restrict__ b4, const float* __restrict__ b5,
    const float* __restrict__ b6, const float* __restrict__ b7,
    const float* __restrict__ b_out,
    const unsigned short* __restrict__ whi, const unsigned short* __restrict__ wlo,
    float* __restrict__ out, float* __restrict__ hfinal) {
  const int g = blockIdx.y;
  const int lane = threadIdx.x & 63;
  const int wv = threadIdx.x >> 6;
  const int q = lane >> 4;
  const int c = lane & 15;
  const int n0 = blockIdx.x * (32 * 4) + wv * 32;  // wave's first point within group

  const unsigned short* wgh = whi + (size_t)g * GROUP_ELEMS;
  const unsigned short* wgl = wlo + (size_t)g * GROUP_ELEMS;

  // prologue: prefetch layer-1 A-hi first (deepest latency cover)
  bf16x8 Ah[4][2];
#pragma unroll
  for (int mt = 0; mt < 4; ++mt)
#pragma unroll
    for (int kt = 0; kt < 2; ++kt)
      Ah[mt][kt] = *(const bf16x8*)(wgh + 1 * SLOT_ELEMS + (mt * 16 + c) * 64 + kt * 32 + q * 8);

  // raw x for this lane's NT points (rebuilt into B frags at L0 and L5)
  float xr[NT][3];
#pragma unroll
  for (int nt = 0; nt < NT; ++nt) {
    const float* xp = x + ((size_t)g * NPTS + n0 + nt * 16 + c) * 3;
    xr[nt][0] = xp[0]; xr[nt][1] = xp[1]; xr[nt][2] = xp[2];
  }

  f32x4 C[4][NT];
  bf16x8 Bh[NT][2], Bl[NT][2];

  // layer 0: x -> 64 (loads its own small A inline)
  zeroC(C);
  xpart(wgh + 0 * SLOT_ELEMS, wgl + 0 * SLOT_ELEMS, q, c, xr, C);
  cvt_all<false>(C, (const float4*)(b0 + g * 64), q, Bh, Bl);

  // layers 1..4 (pipelined)
  zeroC(C); dense_pipe(wgl + 1 * SLOT_ELEMS, wgh + 2 * SLOT_ELEMS, q, c, Bh, Bl, C, Ah);
  cvt_all<false>(C, (const float4*)(b1 + g * 64), q, Bh, Bl);
  zeroC(C); dense_pipe(wgl + 2 * SLOT_ELEMS, wgh + 3 * SLOT_ELEMS, q, c, Bh, Bl, C, Ah);
  cvt_all<false>(C, (const float4*)(b2 + g * 64), q, Bh, Bl);
  zeroC(C); dense_pipe(wgl + 3 * SLOT_ELEMS, wgh + 4 * SLOT_ELEMS, q, c, Bh, Bl, C, Ah);
  cvt_all<false>(C, (const float4*)(b3 + g * 64), q, Bh, Bl);
  zeroC(C); dense_pipe(wgl + 4 * SLOT_ELEMS, wgh + 5 * SLOT_ELEMS, q, c, Bh, Bl, C, Ah);
  cvt_all<false>(C, (const float4*)(b4 + g * 64), q, Bh, Bl);

  // layer 5: concat([x, h4]) -> x-part (slot 8, inline loads) + dense h-part (slot 5)
  zeroC(C);
  xpart(wgh + 8 * SLOT_ELEMS, wgl + 8 * SLOT_ELEMS, q, c, xr, C);
  dense_pipe(wgl + 5 * SLOT_ELEMS, wgh + 6 * SLOT_ELEMS, q, c, Bh, Bl, C, Ah);
  cvt_all<false>(C, (const float4*)(b5 + g * 64), q, Bh, Bl);

  // layers 6..7; layer 7 prefetches w_out (slot 9) hi frags
  zeroC(C); dense_pipe(wgl + 6 * SLOT_ELEMS, wgh + 7 * SLOT_ELEMS, q, c, Bh, Bl, C, Ah);
  cvt_all<false>(C, (const float4*)(b6 + g * 64), q, Bh, Bl);
  zeroC(C); dense_pipe(wgl + 7 * SLOT_ELEMS, wgh + 9 * SLOT_ELEMS, q, c, Bh, Bl, C, Ah);
  cvt_all<true>(C, (const float4*)(b7 + g * 64), q, Bh, Bl);  // leaves relu'd h in C

  // write hfinal (fp32, post-relu, from C; feature = mt*16+q*4+r)
#pragma unroll
  for (int mt = 0; mt < 4; ++mt) {
#pragma unroll
    for (int nt = 0; nt < NT; ++nt) {
      size_t ptg = (size_t)g * NPTS + n0 + nt * 16 + c;
      f32x4 v = C[mt][nt];
      *(float4*)(hfinal + ptg * 64 + mt * 16 + q * 4) = make_float4(v[0], v[1], v[2], v[3]);
    }
  }

  // out layer: 64 -> 4. Slot-9 hi frags already in Ah[0] (rows c of [16][64];
  // rows 4..15 are zero). Result rows 0..3 live in q==0 lanes.
  f32x4 Co[NT];
#pragma unroll
  for (int nt = 0; nt < NT; ++nt) {
    f32x4 z = {0.f, 0.f, 0.f, 0.f};
    Co[nt] = z;
  }
#pragma unroll
  for (int kt = 0; kt < 2; ++kt) {
    bf16x8 Al = *(const bf16x8*)(wgl + 9 * SLOT_ELEMS + c * 64 + kt * 32 + q * 8);
#pragma unroll
    for (int nt = 0; nt < NT; ++nt) {
      Co[nt] = MFMA16(Ah[0][kt], Bh[nt][kt], Co[nt]);
      Co[nt] = MFMA16(Ah[0][kt], Bl[nt][kt], Co[nt]);
      Co[nt] = MFMA16(Al, Bh[nt][kt], Co[nt]);
    }
  }
  if (q == 0) {
    float4 bo = *(const float4*)(b_out + g * 4);
#pragma unroll
    for (int nt = 0; nt < NT; ++nt) {
      size_t ptg = (size_t)g * NPTS + n0 + nt * 16 + c;
      *(float4*)(out + ptg * 4) =
          make_float4(Co[nt][0] + bo.x, Co[nt][1] + bo.y, Co[nt][2] + bo.z, Co[nt][3] + bo.w);
    }
  }
}

extern "C" void kernel_launch(void* const* d_in, const int* in_sizes, int n_in,
                              void* d_out, int out_size, void* d_ws, size_t ws_size,
                              hipStream_t stream) {
  const float* x  = (const float*)d_in[0];
  const float* w0 = (const float*)d_in[1];  const float* b0 = (const float*)d_in[2];
  const float* w1 = (const float*)d_in[3];  const float* b1 = (const float*)d_in[4];
  const float* w2 = (const float*)d_in[5];  const float* b2 = (const float*)d_in[6];
  const float* w3 = (const float*)d_in[7];  const float* b3 = (const float*)d_in[8];
  const float* w4 = (const float*)d_in[9];  const float* b4 = (const float*)d_in[10];
  const float* w5 = (const float*)d_in[11]; const float* b5 = (const float*)d_in[12];
  const float* w6 = (const float*)d_in[13]; const float* b6 = (const float*)d_in[14];
  const float* w7 = (const float*)d_in[15]; const float* b7 = (const float*)d_in[16];
  const float* w_out = (const float*)d_in[17];
  const float* b_out = (const float*)d_in[18];

  float* out    = (float*)d_out;                          // [G,N,4]
  float* hfinal = (float*)d_out + (size_t)NG * NPTS * 4;  // [G,N,64]

  unsigned short* whi = (unsigned short*)d_ws;
  unsigned short* wlo = whi + WBUF_ELEMS;

  prep_weights<<<dim3((WBUF_ELEMS + 255) / 256), dim3(256), 0, stream>>>(
      w0, w1, w2, w3, w4, w5, w6, w7, w_out, whi, wlo);

  mlp_mfma_kernel<<<dim3(NPTS / 128, NG), dim3(256), 0, stream>>>(
      x, b0, b1, b2, b3, b4, b5, b6, b7, b_out, whi, wlo, out, hfinal);
}